// Round 21
// baseline (193.069 us; speedup 1.0000x reference)
//
#include <hip/hip_runtime.h>
#include <hip/hip_bf16.h>

// Problem dims
#define B_  32
#define C_  16
#define Hh  64
#define Ww  64
#define O_  256
#define Kk  5
#define Ho_ 60
#define Wo_ 60
#define Dd  400                 // C*K*K
#define Nn  (B_*Ho_*Wo_)        // 115200
#define NY  ((size_t)B_*O_*Ho_*Wo_)  // 29491200
#define ACAP 16384
#define OVCAP 1024
#define TAU 2.5e-4f             // top-2 gap threshold (bf16x3 max err ~1e-5)
#define NSL 16                  // delta slices per o
#define NCHK 60                 // counting-sort chunks (1920 rows each)

typedef float f4 __attribute__((ext_vector_type(4)));
typedef float f32x16 __attribute__((ext_vector_type(16)));
typedef unsigned int u32x2 __attribute__((ext_vector_type(2)));
typedef unsigned int u32x4 __attribute__((ext_vector_type(4)));
typedef __bf16 bf16x8 __attribute__((ext_vector_type(8)));

static __device__ __forceinline__ void bf16split(float v, unsigned short& h, unsigned short& l) {
    __hip_bfloat16 bh = __float2bfloat16(v);
    float vh = __bfloat162float(bh);
    __hip_bfloat16 bl = __float2bfloat16(v - vh);
    h = __builtin_bit_cast(unsigned short, bh);
    l = __builtin_bit_cast(unsigned short, bl);
}

// ---- prep: pack w as MFMA-A fragments; zero counters AND dout delta region ----
__global__ void prep_kernel(const float* __restrict__ w, unsigned short* __restrict__ wpkH,
                            unsigned short* __restrict__ wpkL, int* __restrict__ acnt,
                            int* __restrict__ ovcnt, int* __restrict__ done,
                            float* __restrict__ dout) {
    const int u = blockIdx.x;           // 0..24
    const int jc = u / 5, s5 = u - (u / 5) * 5;
    const int tid = threadIdx.x;
    const int ot = tid >> 5, r32 = tid & 31;   // ot 0..7
    const int o = 32 * ot + r32;
    #pragma unroll
    for (int q2 = 0; q2 < 2; ++q2) {
        unsigned short h[8], l[8];
        #pragma unroll
        for (int j = 0; j < 8; ++j) {
            int g = 16 * s5 + 8 * q2 + j;
            bf16split(w[o * Dd + g * 5 + jc], h[j], l[j]);
        }
        const size_t off = ((size_t)(u * 8 + ot) * 64 + (r32 + 32 * q2)) * 8;
        u32x4 ph = { (unsigned)h[0] | ((unsigned)h[1] << 16), (unsigned)h[2] | ((unsigned)h[3] << 16),
                     (unsigned)h[4] | ((unsigned)h[5] << 16), (unsigned)h[6] | ((unsigned)h[7] << 16) };
        u32x4 pl = { (unsigned)l[0] | ((unsigned)l[1] << 16), (unsigned)l[2] | ((unsigned)l[3] << 16),
                     (unsigned)l[4] | ((unsigned)l[5] << 16), (unsigned)l[6] | ((unsigned)l[7] << 16) };
        *reinterpret_cast<u32x4*>(wpkH + off) = ph;
        *reinterpret_cast<u32x4*>(wpkL + off) = pl;
    }
    // zero dout delta region: 25 blocks * 256 threads * 16 floats = 102400 = O_*Dd exactly
    {
        float* dz = dout + NY + ((size_t)u * 256 + tid) * 16;
        f4 z = { 0.f, 0.f, 0.f, 0.f };
        *reinterpret_cast<f4*>(dz)      = z;
        *reinterpret_cast<f4*>(dz + 4)  = z;
        *reinterpret_cast<f4*>(dz + 8)  = z;
        *reinterpret_cast<f4*>(dz + 12) = z;
    }
    if (u == 0 && tid == 0) { *acnt = 0; *ovcnt = 0; *done = 0; }
}

// ---- phase 1: 32x32x16 bf16x3 MFMA conv; winner map (NO atomics); NT y-stores ----
__launch_bounds__(256, 3)
__global__ void conv_mfma_kernel(const float* __restrict__ x, const unsigned short* __restrict__ wpkH,
                                 const unsigned short* __restrict__ wpkL, float* __restrict__ y,
                                 unsigned short* __restrict__ winner, float* __restrict__ wsv,
                                 int* __restrict__ acnt, int* __restrict__ ambig) {
    __shared__ __align__(16) unsigned short xT[2 * 7072];   // [plane][v 0..67][g 0..103(pad)]
    __shared__ float wm1[4][64], wm2[4][64];
    __shared__ float rowM1[64];
    __shared__ float rowMv[64];
    __shared__ int   rowO[64];

    const int tid = threadIdx.x;
    const int L = tid & 63, wv = tid >> 6;
    const int q2 = L >> 5, r32 = L & 31;
    const int bid = (int)((blockIdx.x & 7) * 240 + (blockIdx.x >> 3));   // XCD swizzle
    const int b = bid / Ho_, ho = bid % Ho_;

    const unsigned short* ah0 = wpkH + (size_t)(2 * wv) * 512 + (size_t)L * 8;
    const unsigned short* al0 = wpkL + (size_t)(2 * wv) * 512 + (size_t)L * 8;

    // A TRIPLE buffer (depth-2 prefetch); issue steps 0,1 NOW
    u32x4 AH_[3][2], AL_[3][2];
    #pragma unroll
    for (int ot = 0; ot < 2; ++ot) {
        AH_[0][ot] = *reinterpret_cast<const u32x4*>(ah0 + ot * 512);
        AL_[0][ot] = *reinterpret_cast<const u32x4*>(al0 + ot * 512);
        AH_[1][ot] = *reinterpret_cast<const u32x4*>(ah0 + 4096 + ot * 512);
        AL_[1][ot] = *reinterpret_cast<const u32x4*>(al0 + 4096 + ot * 512);
    }

    // zero rows v=64..67 (cols 0..79), both planes
    if (tid < 80) {
        u32x4 z = { 0, 0, 0, 0 };
        int plane = tid / 40, rem = tid % 40, row = 64 + rem / 10, blk = rem % 10;
        *reinterpret_cast<u32x4*>(&xT[plane * 7072 + row * 104 + blk * 8]) = z;
    }

    // stage x transposed (column-gather)
    {
        const float* xb = x + (size_t)b * (C_ * Hh * Ww);
        const int v = tid & 63;
        const int seg = tid >> 6;
        const int segc = seg * 4;
        #pragma unroll
        for (int qg = 0; qg < 5; ++qg) {
            unsigned short h[4], l[4];
            #pragma unroll
            for (int gg = 0; gg < 4; ++gg) {
                const int k = qg * 4 + gg;
                const int kc = k / 5, ki = k % 5;
                float val = xb[((segc + kc) * Hh + ho + ki) * Ww + v];
                bf16split(val, h[gg], l[gg]);
            }
            const int g0 = seg * 20 + qg * 4;
            u32x2 ph = { (unsigned)h[0] | ((unsigned)h[1] << 16),
                         (unsigned)h[2] | ((unsigned)h[3] << 16) };
            u32x2 pl = { (unsigned)l[0] | ((unsigned)l[1] << 16),
                         (unsigned)l[2] | ((unsigned)l[3] << 16) };
            *reinterpret_cast<u32x2*>(&xT[v * 104 + g0]) = ph;
            *reinterpret_cast<u32x2*>(&xT[7072 + v * 104 + g0]) = pl;
        }
    }

    f32x16 acc[2][2];   // [ot][wt]
    #pragma unroll
    for (int ot = 0; ot < 2; ++ot)
        #pragma unroll
        for (int wt = 0; wt < 2; ++wt)
            #pragma unroll
            for (int i = 0; i < 16; ++i) acc[ot][wt][i] = 0.f;

    __syncthreads();

    // B double buffer; step-0 ds_reads
    u32x4 BH_[2][2], BL_[2][2];
    #pragma unroll
    for (int wt = 0; wt < 2; ++wt) {
        const int bbase = (32 * wt + r32 + 0) * 104 + 0 + 8 * q2;   // jc=0, s5=0
        BH_[0][wt] = *reinterpret_cast<const u32x4*>(&xT[bbase]);
        BL_[0][wt] = *reinterpret_cast<const u32x4*>(&xT[7072 + bbase]);
    }

    #pragma unroll
    for (int u = 0; u < 25; ++u) {
        const int cur = u % 3;
        const int curB = u & 1, nxtB = curB ^ 1;
        if (u < 23) {
            const int nxtA = (u + 2) % 3;
            #pragma unroll
            for (int ot = 0; ot < 2; ++ot) {
                AH_[nxtA][ot] = *reinterpret_cast<const u32x4*>(ah0 + (u + 2) * 4096 + ot * 512);
                AL_[nxtA][ot] = *reinterpret_cast<const u32x4*>(al0 + (u + 2) * 4096 + ot * 512);
            }
        }
        if (u < 24) {
            const int jcn = (u + 1) / 5, s5n = (u + 1) % 5;
            #pragma unroll
            for (int wt = 0; wt < 2; ++wt) {
                const int bbase = (32 * wt + r32 + jcn) * 104 + 16 * s5n + 8 * q2;
                BH_[nxtB][wt] = *reinterpret_cast<const u32x4*>(&xT[bbase]);
                BL_[nxtB][wt] = *reinterpret_cast<const u32x4*>(&xT[7072 + bbase]);
            }
        }
        __builtin_amdgcn_sched_barrier(0);
        #pragma unroll
        for (int p = 0; p < 3; ++p) {
            #pragma unroll
            for (int ot = 0; ot < 2; ++ot) {
                #pragma unroll
                for (int wt = 0; wt < 2; ++wt) {
                    bf16x8 Aop = __builtin_bit_cast(bf16x8, (p == 2) ? AL_[cur][ot] : AH_[cur][ot]);
                    bf16x8 Bop = __builtin_bit_cast(bf16x8, (p == 1) ? BL_[curB][wt] : BH_[curB][wt]);
                    acc[ot][wt] = __builtin_amdgcn_mfma_f32_32x32x16_bf16(Aop, Bop, acc[ot][wt], 0, 0, 0);
                }
            }
        }
    }

    // ---- per-wo top-2 over this wave's 64 o's
    #pragma unroll
    for (int wt = 0; wt < 2; ++wt) {
        float m1 = -__builtin_inff(), m2 = -__builtin_inff();
        #pragma unroll
        for (int ot = 0; ot < 2; ++ot)
            #pragma unroll
            for (int i = 0; i < 16; ++i) {
                float v = acc[ot][wt][i];
                m2 = fmaxf(m2, fminf(m1, v));
                m1 = fmaxf(m1, v);
            }
        float o1 = __shfl_xor(m1, 32), o2 = __shfl_xor(m2, 32);
        m2 = fmaxf(fminf(m1, o1), fmaxf(m2, o2));
        m1 = fmaxf(m1, o1);
        if (q2 == 0) { wm1[wv][32 * wt + r32] = m1; wm2[wv][32 * wt + r32] = m2; }
    }
    __syncthreads();
    if (tid < 64) {
        const int p = tid;
        float M1 = wm1[0][p], M2 = wm2[0][p];
        #pragma unroll
        for (int w2 = 1; w2 < 4; ++w2) {
            float c1 = wm1[w2][p], c2 = wm2[w2][p];
            M2 = fmaxf(fminf(M1, c1), fmaxf(M2, c2));
            M1 = fmaxf(M1, c1);
        }
        bool amb = (M1 - M2) < TAU;     // bitwise ties give gap 0 -> always ambiguous
        if (amb && p < Wo_) {
            int n = (b * Ho_ + ho) * Wo_ + p;
            int pos = atomicAdd(acnt, 1);
            if (pos < ACAP) ambig[pos] = n;
        }
        rowM1[p] = amb ? __builtin_inff() : M1;   // INF suppresses match for amb rows
        rowMv[p] = M1;
        rowO[p] = 0;
    }
    __syncthreads();

    // ---- winner-o extraction: unique (thread,reg) matches block max; plain LDS store
    #pragma unroll
    for (int wt = 0; wt < 2; ++wt) {
        const int wo = 32 * wt + r32;
        if (wo < Wo_) {
            const float M = rowM1[wo];
            #pragma unroll
            for (int ot = 0; ot < 2; ++ot)
                #pragma unroll
                for (int i = 0; i < 16; ++i) {
                    if (acc[ot][wt][i] == M)
                        rowO[wo] = 64 * wv + 32 * ot + (i & 3) + 8 * (i >> 2) + 4 * q2;
                }
        }
    }
    __syncthreads();
    if (tid < Wo_) {
        const int n = (b * Ho_ + ho) * Wo_ + tid;
        winner[n] = (unsigned short)rowO[tid];
        wsv[n] = rowMv[tid];
    }

    // ---- y stores: nontemporal (keep wpk/x L2-resident)
    #pragma unroll
    for (int ot = 0; ot < 2; ++ot)
        #pragma unroll
        for (int wt = 0; wt < 2; ++wt) {
            const int wo = 32 * wt + r32;
            if (wo < Wo_) {
                #pragma unroll
                for (int i = 0; i < 16; ++i) {
                    const int o = 64 * wv + 32 * ot + (i & 3) + 8 * (i >> 2) + 4 * q2;
                    __builtin_nontemporal_store(acc[ot][wt][i],
                        y + ((size_t)(b * O_ + o) * Ho_ + ho) * (size_t)Wo_ + wo);
                }
            }
        }
}

// ---- fallback: exact fp32 re-resolve of ambiguous rows; writes winner map + overflow ties ----
__global__ void fallback_kernel(const float* __restrict__ x, const float* __restrict__ w,
                                const int* __restrict__ acnt, const int* __restrict__ ambig,
                                unsigned short* __restrict__ winner, float* __restrict__ wsv,
                                int* __restrict__ ovn, int* __restrict__ ovo,
                                float* __restrict__ ovs, int* __restrict__ ovcnt) {
    __shared__ float xrow[Dd];
    __shared__ float red[256];
    __shared__ int nm;
    int cnt = *acnt; if (cnt > ACAP) cnt = ACAP;
    for (int idx = blockIdx.x; idx < cnt; idx += gridDim.x) {
        const int n = ambig[idx];
        const int bb = n / 3600, rem = n % 3600, hh = rem / 60, ww2 = rem % 60;
        for (int k = threadIdx.x; k < Dd; k += 256) {
            int c = k / 25, rr = k % 25, i = rr / 5, j = rr % 5;
            xrow[k] = x[(((size_t)bb * C_ + c) * Hh + hh + i) * Ww + ww2 + j];
        }
        __syncthreads();
        const int o = threadIdx.x;
        const float* wr = w + (size_t)o * Dd;
        float s = 0.f;
        #pragma unroll 4
        for (int k = 0; k < Dd; ++k) s = fmaf(xrow[k], wr[k], s);
        red[o] = s;
        if (o == 0) nm = 0;
        __syncthreads();
        #pragma unroll
        for (int st = 128; st >= 1; st >>= 1) {
            if (o < st) red[o] = fmaxf(red[o], red[o + st]);
            __syncthreads();
        }
        const float mx = red[0];
        if (s == mx) {
            int k2 = atomicAdd(&nm, 1);                // LDS atomic
            if (k2 == 0) { winner[n] = (unsigned short)o; wsv[n] = s; }
            else {                                     // true tie (rare): overflow
                int q = atomicAdd(ovcnt, 1);
                if (q < OVCAP) { ovn[q] = n; ovo[q] = o; ovs[q] = s; }
            }
        }
        __syncthreads();
    }
}

// ---- fused counting sort: hist + device-scope barrier + prefix + scatter (60 blocks) ----
__global__ void sort_kernel(const unsigned short* __restrict__ winner, const float* __restrict__ wsv,
                            int* __restrict__ h, int* __restrict__ done,
                            const int* __restrict__ ovn, const int* __restrict__ ovo,
                            const float* __restrict__ ovs, const int* __restrict__ ovcnt,
                            int* __restrict__ lw_n, float* __restrict__ lw_s,
                            int* __restrict__ count, int cap) {
    __shared__ int lh[O_];
    __shared__ int cur[O_];
    const int blk = blockIdx.x, tid = threadIdx.x;
    lh[tid] = 0;
    __syncthreads();
    const int n0 = blk * (Nn / NCHK);
    for (int i = tid; i < Nn / NCHK; i += 256)
        atomicAdd(&lh[(int)winner[n0 + i]], 1);       // LDS atomic
    __syncthreads();
    h[blk * O_ + tid] = lh[tid];
    __threadfence();                                   // release h device-wide
    __syncthreads();
    if (tid == 0) {
        atomicAdd(done, 1);                            // device-scope arrival
        while (atomicAdd(done, 0) < NCHK) __builtin_amdgcn_s_sleep(8);
        __threadfence();                               // acquire
    }
    __syncthreads();
    // per-o base for this chunk = sum of h over chunks < blk
    int basev = 0;
    for (int bb = 0; bb < blk; ++bb) basev += h[bb * O_ + tid];
    cur[tid] = basev;
    // block 0: totals + overflow placement + count
    if (blk == 0) {
        int tot = 0;
        for (int bb = 0; bb < NCHK; ++bb) tot += h[bb * O_ + tid];
        int oc = *ovcnt; if (oc > OVCAP) oc = OVCAP;
        int cnt = tot;
        for (int e = 0; e < oc; ++e) {
            if (ovo[e] == tid && cnt < cap) {
                lw_n[(size_t)tid * cap + cnt] = ovn[e];
                lw_s[(size_t)tid * cap + cnt] = ovs[e];
                ++cnt;
            }
        }
        count[tid] = (cnt < cap) ? cnt : cap;
    }
    __syncthreads();
    // scatter my chunk into partitioned positions
    for (int i = tid; i < Nn / NCHK; i += 256) {
        const int n = n0 + i;
        const int o = (int)winner[n];
        int pos = atomicAdd(&cur[o], 1);               // LDS atomic
        if (pos < cap) {
            lw_n[(size_t)o * cap + pos] = n;
            lw_s[(size_t)o * cap + pos] = wsv[n];
        }
    }
}

// ---- phase 2: per-slice sums, ATOMIC-accumulated directly into dout ----
__global__ void delta_part_kernel(const float* __restrict__ x, const float* __restrict__ w,
                                  const int* __restrict__ count, const int* __restrict__ lw_n,
                                  const float* __restrict__ lw_s, float* __restrict__ dout,
                                  int cap) {
    const int o   = blockIdx.x / NSL;
    const int sl  = blockIdx.x % NSL;
    const int tid = threadIdx.x;
    int cnt = count[o]; if (cnt > cap) cnt = cap;
    const int e0 = (int)(((long long)cnt * sl) / NSL);
    const int e1 = (int)(((long long)cnt * (sl + 1)) / NSL);

    const int d0 = tid;
    const int c0 = d0 / 25, r0 = d0 % 25, i0 = r0 / 5, j0 = r0 % 5;
    const bool has1 = (tid < Dd - 256);
    const int dd1 = has1 ? tid + 256 : 0;
    const int c1 = dd1 / 25, r1 = dd1 % 25, i1 = r1 / 5, j1 = r1 % 5;
    const int off0 = c0 * (Hh * Ww) + i0 * Ww + j0;
    const int off1 = c1 * (Hh * Ww) + i1 * Ww + j1;

    const int* ln = lw_n + (size_t)o * cap;
    const float* ls = lw_s + (size_t)o * cap;

    float acc0 = 0.f, acc1 = 0.f, ssum = 0.f;
    int nA = 0, nB = 0; float sA = 0.f, sB = 0.f;
    if (e0 < e1)     { nA = ln[e0];     sA = ls[e0]; }
    if (e0 + 1 < e1) { nB = ln[e0 + 1]; sB = ls[e0 + 1]; }
    float xA0 = 0.f, xA1 = 0.f;
    if (e0 < e1) {
        int bb = nA / 3600, rem = nA - bb * 3600, hh = rem / 60, ww2 = rem - hh * 60;
        const float* xb = x + (size_t)bb * (C_ * Hh * Ww) + hh * Ww + ww2;
        xA0 = xb[off0]; if (has1) xA1 = xb[off1];
    }
    for (int e = e0; e < e1; ++e) {
        float xB0 = 0.f, xB1 = 0.f;
        if (e + 1 < e1) {
            int bb = nB / 3600, rem = nB - bb * 3600, hh = rem / 60, ww2 = rem - hh * 60;
            const float* xb = x + (size_t)bb * (C_ * Hh * Ww) + hh * Ww + ww2;
            xB0 = xb[off0]; if (has1) xB1 = xb[off1];
        }
        int nC = 0; float sC = 0.f;
        if (e + 2 < e1) { nC = ln[e + 2]; sC = ls[e + 2]; }
        ssum += sA; acc0 += sA * xA0; acc1 += sA * xA1;
        nA = nB; sA = sB; xA0 = xB0; xA1 = xB1;
        nB = nC; sB = sC;
    }
    if (e0 < e1) {
        const float invN = 1.0f / (float)Nn;
        atomicAdd(dout + NY + (size_t)o * Dd + d0, acc0 * invN - ssum * invN * w[o * Dd + d0]);
        if (has1)
            atomicAdd(dout + NY + (size_t)o * Dd + dd1, acc1 * invN - ssum * invN * w[o * Dd + dd1]);
    }
}

extern "C" void kernel_launch(void* const* d_in, const int* in_sizes, int n_in,
                              void* d_out, int out_size, void* d_ws, size_t ws_size,
                              hipStream_t stream) {
    (void)in_sizes; (void)n_in; (void)out_size;
    const float* x = (const float*)d_in[0];
    const float* w = (const float*)d_in[1];
    float* out = (float*)d_out;

    char* ws = (char*)d_ws;
    int*            count  = (int*)ws;                         // @0         (1,024 B)
    int*            acnt   = (int*)(ws + 1024);                // @1,024     (64 B)
    int*            ovcnt  = (int*)(ws + 1088);                // @1,088     (64 B)
    int*            done   = (int*)(ws + 1152);                // @1,152     (64 B)
    int*            ambig  = (int*)(ws + 1216);                // @1,216     (65,536 B)
    unsigned short* wpkH   = (unsigned short*)(ws + 66752);    // @66,752    (204,800 B)
    unsigned short* wpkL   = (unsigned short*)(ws + 271552);   // @271,552   (204,800 B)
    unsigned short* winner = (unsigned short*)(ws + 476352);   // @476,352   (230,400 B)
    float*          wsv    = (float*)(ws + 706752);            // @706,752   (460,800 B)
    int*            ovn    = (int*)(ws + 1167552);             // @1,167,552 (4,096 B)
    int*            ovo    = (int*)(ws + 1171648);             // @1,171,648 (4,096 B)
    float*          ovs    = (float*)(ws + 1175744);           // @1,175,744 (4,096 B)
    int*            hist   = (int*)(ws + 1179840);             // @1,179,840 (61,440 B)
    const size_t base = 1241280;

    size_t avail = (ws_size > base) ? (ws_size - base) : 0;
    long long cap_ll = (long long)(avail / ((size_t)O_ * 8));
    int cap = (int)(cap_ll > 4096 ? 4096 : (cap_ll < 1 ? 1 : cap_ll));

    int*   lw_n = (int*)(ws + base);
    float* lw_s = (float*)(ws + base + (size_t)O_ * cap * 4);

    prep_kernel<<<dim3(25), dim3(256), 0, stream>>>(w, wpkH, wpkL, acnt, ovcnt, done, out);
    conv_mfma_kernel<<<dim3(B_ * Ho_), dim3(256), 0, stream>>>(x, wpkH, wpkL, out, winner, wsv,
                                                               acnt, ambig);
    fallback_kernel<<<dim3(256), dim3(256), 0, stream>>>(x, w, acnt, ambig, winner, wsv,
                                                         ovn, ovo, ovs, ovcnt);
    sort_kernel<<<dim3(NCHK), dim3(256), 0, stream>>>(winner, wsv, hist, done,
                                                      ovn, ovo, ovs, ovcnt,
                                                      lw_n, lw_s, count, cap);
    delta_part_kernel<<<dim3(O_ * NSL), dim3(256), 0, stream>>>(x, w, count, lw_n, lw_s, out, cap);
}

// Round 22
// 182.596 us; speedup vs baseline: 1.0574x; 1.0574x over previous
//
#include <hip/hip_runtime.h>
#include <hip/hip_bf16.h>

// Problem dims
#define B_  32
#define C_  16
#define Hh  64
#define Ww  64
#define O_  256
#define Kk  5
#define Ho_ 60
#define Wo_ 60
#define Dd  400                 // C*K*K
#define Nn  (B_*Ho_*Wo_)        // 115200
#define NY  ((size_t)B_*O_*Ho_*Wo_)  // 29491200
#define ACAP 16384
#define OVCAP 1024
#define TAU 2.5e-4f             // top-2 gap threshold (bf16x3 max err ~1e-5)
#define NSL 16                  // delta slices per o
#define NCHK 60                 // counting-sort chunks (1920 rows each)

typedef float f4 __attribute__((ext_vector_type(4)));
typedef float f32x16 __attribute__((ext_vector_type(16)));
typedef unsigned int u32x2 __attribute__((ext_vector_type(2)));
typedef unsigned int u32x4 __attribute__((ext_vector_type(4)));
typedef __bf16 bf16x8 __attribute__((ext_vector_type(8)));

static __device__ __forceinline__ void bf16split(float v, unsigned short& h, unsigned short& l) {
    __hip_bfloat16 bh = __float2bfloat16(v);
    float vh = __bfloat162float(bh);
    __hip_bfloat16 bl = __float2bfloat16(v - vh);
    h = __builtin_bit_cast(unsigned short, bh);
    l = __builtin_bit_cast(unsigned short, bl);
}

// ---- prep: pack w as MFMA-A fragments; zero counters AND dout delta region ----
__global__ void prep_kernel(const float* __restrict__ w, unsigned short* __restrict__ wpkH,
                            unsigned short* __restrict__ wpkL, int* __restrict__ acnt,
                            int* __restrict__ ovcnt, float* __restrict__ dout) {
    const int u = blockIdx.x;           // 0..24
    const int jc = u / 5, s5 = u - (u / 5) * 5;
    const int tid = threadIdx.x;
    const int ot = tid >> 5, r32 = tid & 31;   // ot 0..7
    const int o = 32 * ot + r32;
    #pragma unroll
    for (int q2 = 0; q2 < 2; ++q2) {
        unsigned short h[8], l[8];
        #pragma unroll
        for (int j = 0; j < 8; ++j) {
            int g = 16 * s5 + 8 * q2 + j;
            bf16split(w[o * Dd + g * 5 + jc], h[j], l[j]);
        }
        const size_t off = ((size_t)(u * 8 + ot) * 64 + (r32 + 32 * q2)) * 8;
        u32x4 ph = { (unsigned)h[0] | ((unsigned)h[1] << 16), (unsigned)h[2] | ((unsigned)h[3] << 16),
                     (unsigned)h[4] | ((unsigned)h[5] << 16), (unsigned)h[6] | ((unsigned)h[7] << 16) };
        u32x4 pl = { (unsigned)l[0] | ((unsigned)l[1] << 16), (unsigned)l[2] | ((unsigned)l[3] << 16),
                     (unsigned)l[4] | ((unsigned)l[5] << 16), (unsigned)l[6] | ((unsigned)l[7] << 16) };
        *reinterpret_cast<u32x4*>(wpkH + off) = ph;
        *reinterpret_cast<u32x4*>(wpkL + off) = pl;
    }
    // zero dout delta region: 25 blocks * 256 threads * 16 floats = 102400 = O_*Dd exactly
    {
        float* dz = dout + NY + ((size_t)u * 256 + tid) * 16;
        f4 z = { 0.f, 0.f, 0.f, 0.f };
        *reinterpret_cast<f4*>(dz)      = z;
        *reinterpret_cast<f4*>(dz + 4)  = z;
        *reinterpret_cast<f4*>(dz + 8)  = z;
        *reinterpret_cast<f4*>(dz + 12) = z;
    }
    if (u == 0 && tid == 0) { *acnt = 0; *ovcnt = 0; }
}

// ---- phase 1: 32x32x16 bf16x3 MFMA conv; winner map (NO atomics); NT y-stores ----
__launch_bounds__(256, 3)
__global__ void conv_mfma_kernel(const float* __restrict__ x, const unsigned short* __restrict__ wpkH,
                                 const unsigned short* __restrict__ wpkL, float* __restrict__ y,
                                 unsigned short* __restrict__ winner, float* __restrict__ wsv,
                                 int* __restrict__ acnt, int* __restrict__ ambig) {
    __shared__ __align__(16) unsigned short xT[2 * 7072];   // [plane][v 0..67][g 0..103(pad)]
    __shared__ float wm1[4][64], wm2[4][64];
    __shared__ float rowM1[64];
    __shared__ float rowMv[64];
    __shared__ int   rowO[64];

    const int tid = threadIdx.x;
    const int L = tid & 63, wv = tid >> 6;
    const int q2 = L >> 5, r32 = L & 31;
    const int bid = (int)((blockIdx.x & 7) * 240 + (blockIdx.x >> 3));   // XCD swizzle
    const int b = bid / Ho_, ho = bid % Ho_;

    const unsigned short* ah0 = wpkH + (size_t)(2 * wv) * 512 + (size_t)L * 8;
    const unsigned short* al0 = wpkL + (size_t)(2 * wv) * 512 + (size_t)L * 8;

    // A TRIPLE buffer (depth-2 prefetch); issue steps 0,1 NOW
    u32x4 AH_[3][2], AL_[3][2];
    #pragma unroll
    for (int ot = 0; ot < 2; ++ot) {
        AH_[0][ot] = *reinterpret_cast<const u32x4*>(ah0 + ot * 512);
        AL_[0][ot] = *reinterpret_cast<const u32x4*>(al0 + ot * 512);
        AH_[1][ot] = *reinterpret_cast<const u32x4*>(ah0 + 4096 + ot * 512);
        AL_[1][ot] = *reinterpret_cast<const u32x4*>(al0 + 4096 + ot * 512);
    }

    // zero rows v=64..67 (cols 0..79), both planes
    if (tid < 80) {
        u32x4 z = { 0, 0, 0, 0 };
        int plane = tid / 40, rem = tid % 40, row = 64 + rem / 10, blk = rem % 10;
        *reinterpret_cast<u32x4*>(&xT[plane * 7072 + row * 104 + blk * 8]) = z;
    }

    // stage x transposed (column-gather)
    {
        const float* xb = x + (size_t)b * (C_ * Hh * Ww);
        const int v = tid & 63;
        const int seg = tid >> 6;
        const int segc = seg * 4;
        #pragma unroll
        for (int qg = 0; qg < 5; ++qg) {
            unsigned short h[4], l[4];
            #pragma unroll
            for (int gg = 0; gg < 4; ++gg) {
                const int k = qg * 4 + gg;
                const int kc = k / 5, ki = k % 5;
                float val = xb[((segc + kc) * Hh + ho + ki) * Ww + v];
                bf16split(val, h[gg], l[gg]);
            }
            const int g0 = seg * 20 + qg * 4;
            u32x2 ph = { (unsigned)h[0] | ((unsigned)h[1] << 16),
                         (unsigned)h[2] | ((unsigned)h[3] << 16) };
            u32x2 pl = { (unsigned)l[0] | ((unsigned)l[1] << 16),
                         (unsigned)l[2] | ((unsigned)l[3] << 16) };
            *reinterpret_cast<u32x2*>(&xT[v * 104 + g0]) = ph;
            *reinterpret_cast<u32x2*>(&xT[7072 + v * 104 + g0]) = pl;
        }
    }

    f32x16 acc[2][2];   // [ot][wt]
    #pragma unroll
    for (int ot = 0; ot < 2; ++ot)
        #pragma unroll
        for (int wt = 0; wt < 2; ++wt)
            #pragma unroll
            for (int i = 0; i < 16; ++i) acc[ot][wt][i] = 0.f;

    __syncthreads();

    // B double buffer; step-0 ds_reads
    u32x4 BH_[2][2], BL_[2][2];
    #pragma unroll
    for (int wt = 0; wt < 2; ++wt) {
        const int bbase = (32 * wt + r32 + 0) * 104 + 0 + 8 * q2;   // jc=0, s5=0
        BH_[0][wt] = *reinterpret_cast<const u32x4*>(&xT[bbase]);
        BL_[0][wt] = *reinterpret_cast<const u32x4*>(&xT[7072 + bbase]);
    }

    #pragma unroll
    for (int u = 0; u < 25; ++u) {
        const int cur = u % 3;
        const int curB = u & 1, nxtB = curB ^ 1;
        if (u < 23) {
            const int nxtA = (u + 2) % 3;
            #pragma unroll
            for (int ot = 0; ot < 2; ++ot) {
                AH_[nxtA][ot] = *reinterpret_cast<const u32x4*>(ah0 + (u + 2) * 4096 + ot * 512);
                AL_[nxtA][ot] = *reinterpret_cast<const u32x4*>(al0 + (u + 2) * 4096 + ot * 512);
            }
        }
        if (u < 24) {
            const int jcn = (u + 1) / 5, s5n = (u + 1) % 5;
            #pragma unroll
            for (int wt = 0; wt < 2; ++wt) {
                const int bbase = (32 * wt + r32 + jcn) * 104 + 16 * s5n + 8 * q2;
                BH_[nxtB][wt] = *reinterpret_cast<const u32x4*>(&xT[bbase]);
                BL_[nxtB][wt] = *reinterpret_cast<const u32x4*>(&xT[7072 + bbase]);
            }
        }
        __builtin_amdgcn_sched_barrier(0);
        #pragma unroll
        for (int p = 0; p < 3; ++p) {
            #pragma unroll
            for (int ot = 0; ot < 2; ++ot) {
                #pragma unroll
                for (int wt = 0; wt < 2; ++wt) {
                    bf16x8 Aop = __builtin_bit_cast(bf16x8, (p == 2) ? AL_[cur][ot] : AH_[cur][ot]);
                    bf16x8 Bop = __builtin_bit_cast(bf16x8, (p == 1) ? BL_[curB][wt] : BH_[curB][wt]);
                    acc[ot][wt] = __builtin_amdgcn_mfma_f32_32x32x16_bf16(Aop, Bop, acc[ot][wt], 0, 0, 0);
                }
            }
        }
    }

    // ---- per-wo top-2 over this wave's 64 o's
    #pragma unroll
    for (int wt = 0; wt < 2; ++wt) {
        float m1 = -__builtin_inff(), m2 = -__builtin_inff();
        #pragma unroll
        for (int ot = 0; ot < 2; ++ot)
            #pragma unroll
            for (int i = 0; i < 16; ++i) {
                float v = acc[ot][wt][i];
                m2 = fmaxf(m2, fminf(m1, v));
                m1 = fmaxf(m1, v);
            }
        float o1 = __shfl_xor(m1, 32), o2 = __shfl_xor(m2, 32);
        m2 = fmaxf(fminf(m1, o1), fmaxf(m2, o2));
        m1 = fmaxf(m1, o1);
        if (q2 == 0) { wm1[wv][32 * wt + r32] = m1; wm2[wv][32 * wt + r32] = m2; }
    }
    __syncthreads();
    if (tid < 64) {
        const int p = tid;
        float M1 = wm1[0][p], M2 = wm2[0][p];
        #pragma unroll
        for (int w2 = 1; w2 < 4; ++w2) {
            float c1 = wm1[w2][p], c2 = wm2[w2][p];
            M2 = fmaxf(fminf(M1, c1), fmaxf(M2, c2));
            M1 = fmaxf(M1, c1);
        }
        bool amb = (M1 - M2) < TAU;     // bitwise ties give gap 0 -> always ambiguous
        if (amb && p < Wo_) {
            int n = (b * Ho_ + ho) * Wo_ + p;
            int pos = atomicAdd(acnt, 1);
            if (pos < ACAP) ambig[pos] = n;
        }
        rowM1[p] = amb ? __builtin_inff() : M1;   // INF suppresses match for amb rows
        rowMv[p] = M1;
        rowO[p] = 0;
    }
    __syncthreads();

    // ---- winner-o extraction: unique (thread,reg) matches block max; plain LDS store
    #pragma unroll
    for (int wt = 0; wt < 2; ++wt) {
        const int wo = 32 * wt + r32;
        if (wo < Wo_) {
            const float M = rowM1[wo];
            #pragma unroll
            for (int ot = 0; ot < 2; ++ot)
                #pragma unroll
                for (int i = 0; i < 16; ++i) {
                    if (acc[ot][wt][i] == M)
                        rowO[wo] = 64 * wv + 32 * ot + (i & 3) + 8 * (i >> 2) + 4 * q2;
                }
        }
    }
    __syncthreads();
    if (tid < Wo_) {
        const int n = (b * Ho_ + ho) * Wo_ + tid;
        winner[n] = (unsigned short)rowO[tid];
        wsv[n] = rowMv[tid];
    }

    // ---- y stores: nontemporal (keep wpk/x L2-resident)
    #pragma unroll
    for (int ot = 0; ot < 2; ++ot)
        #pragma unroll
        for (int wt = 0; wt < 2; ++wt) {
            const int wo = 32 * wt + r32;
            if (wo < Wo_) {
                #pragma unroll
                for (int i = 0; i < 16; ++i) {
                    const int o = 64 * wv + 32 * ot + (i & 3) + 8 * (i >> 2) + 4 * q2;
                    __builtin_nontemporal_store(acc[ot][wt][i],
                        y + ((size_t)(b * O_ + o) * Ho_ + ho) * (size_t)Wo_ + wo);
                }
            }
        }
}

// ---- fallback: exact fp32 re-resolve of ambiguous rows; writes winner map + overflow ties ----
__global__ void fallback_kernel(const float* __restrict__ x, const float* __restrict__ w,
                                const int* __restrict__ acnt, const int* __restrict__ ambig,
                                unsigned short* __restrict__ winner, float* __restrict__ wsv,
                                int* __restrict__ ovn, int* __restrict__ ovo,
                                float* __restrict__ ovs, int* __restrict__ ovcnt) {
    __shared__ float xrow[Dd];
    __shared__ float red[256];
    __shared__ int nm;
    int cnt = *acnt; if (cnt > ACAP) cnt = ACAP;
    for (int idx = blockIdx.x; idx < cnt; idx += gridDim.x) {
        const int n = ambig[idx];
        const int bb = n / 3600, rem = n % 3600, hh = rem / 60, ww2 = rem % 60;
        for (int k = threadIdx.x; k < Dd; k += 256) {
            int c = k / 25, rr = k % 25, i = rr / 5, j = rr % 5;
            xrow[k] = x[(((size_t)bb * C_ + c) * Hh + hh + i) * Ww + ww2 + j];
        }
        __syncthreads();
        const int o = threadIdx.x;
        const float* wr = w + (size_t)o * Dd;
        float s = 0.f;
        #pragma unroll 4
        for (int k = 0; k < Dd; ++k) s = fmaf(xrow[k], wr[k], s);
        red[o] = s;
        if (o == 0) nm = 0;
        __syncthreads();
        #pragma unroll
        for (int st = 128; st >= 1; st >>= 1) {
            if (o < st) red[o] = fmaxf(red[o], red[o + st]);
            __syncthreads();
        }
        const float mx = red[0];
        if (s == mx) {
            int k2 = atomicAdd(&nm, 1);                // LDS atomic
            if (k2 == 0) { winner[n] = (unsigned short)o; wsv[n] = s; }
            else {                                     // true tie (rare): overflow
                int q = atomicAdd(ovcnt, 1);
                if (q < OVCAP) { ovn[q] = n; ovo[q] = o; ovs[q] = s; }
            }
        }
        __syncthreads();
    }
}

// ---- counting sort pass 1: per-chunk histograms (60 chunks x 1920 rows) ----
__global__ void hist_kernel(const unsigned short* __restrict__ winner, int* __restrict__ h) {
    __shared__ int lh[O_];
    const int blk = blockIdx.x, tid = threadIdx.x;
    lh[tid] = 0;
    __syncthreads();
    const int n0 = blk * (Nn / NCHK);
    #pragma unroll
    for (int i = 0; i < (Nn / NCHK) / 256 + 1; ++i) {
        int idx = tid + i * 256;
        if (idx < Nn / NCHK) atomicAdd(&lh[(int)winner[n0 + idx]], 1);   // LDS atomic
    }
    __syncthreads();
    h[blk * O_ + tid] = lh[tid];
}

// ---- counting sort pass 2: prefix over chunks per o + overflow placement + count ----
__global__ void scan_kernel(const int* __restrict__ h, int* __restrict__ gbase,
                            int* __restrict__ count,
                            const int* __restrict__ ovn, const int* __restrict__ ovo,
                            const float* __restrict__ ovs, const int* __restrict__ ovcnt,
                            int* __restrict__ lw_n, float* __restrict__ lw_s, int cap) {
    const int o = threadIdx.x;          // 1 block, 256 threads
    int run = 0;
    for (int blk = 0; blk < NCHK; ++blk) {
        gbase[blk * O_ + o] = run;
        run += h[blk * O_ + o];
    }
    int oc = *ovcnt; if (oc > OVCAP) oc = OVCAP;
    int cnt = run;
    for (int e = 0; e < oc; ++e) {
        if (ovo[e] == o && cnt < cap) {
            lw_n[(size_t)o * cap + cnt] = ovn[e];
            lw_s[(size_t)o * cap + cnt] = ovs[e];
            ++cnt;
        }
    }
    count[o] = (cnt < cap) ? cnt : cap;
}

// ---- counting sort pass 3: scatter rows into per-o lists (partitioned, no global atomics) ----
__global__ void scatter_kernel(const unsigned short* __restrict__ winner,
                               const float* __restrict__ wsv, const int* __restrict__ gbase,
                               int* __restrict__ lw_n, float* __restrict__ lw_s, int cap) {
    __shared__ int cur[O_];
    const int blk = blockIdx.x, tid = threadIdx.x;
    cur[tid] = gbase[blk * O_ + tid];
    __syncthreads();
    const int n0 = blk * (Nn / NCHK);
    for (int i = tid; i < Nn / NCHK; i += 256) {
        const int n = n0 + i;
        const int o = (int)winner[n];
        int pos = atomicAdd(&cur[o], 1);               // LDS atomic
        if (pos < cap) {
            lw_n[(size_t)o * cap + pos] = n;
            lw_s[(size_t)o * cap + pos] = wsv[n];
        }
    }
}

// ---- phase 2: per-slice sums, ATOMIC-accumulated directly into dout ----
__global__ void delta_part_kernel(const float* __restrict__ x, const float* __restrict__ w,
                                  const int* __restrict__ count, const int* __restrict__ lw_n,
                                  const float* __restrict__ lw_s, float* __restrict__ dout,
                                  int cap) {
    const int o   = blockIdx.x / NSL;
    const int sl  = blockIdx.x % NSL;
    const int tid = threadIdx.x;
    int cnt = count[o]; if (cnt > cap) cnt = cap;
    const int e0 = (int)(((long long)cnt * sl) / NSL);
    const int e1 = (int)(((long long)cnt * (sl + 1)) / NSL);

    const int d0 = tid;
    const int c0 = d0 / 25, r0 = d0 % 25, i0 = r0 / 5, j0 = r0 % 5;
    const bool has1 = (tid < Dd - 256);
    const int dd1 = has1 ? tid + 256 : 0;
    const int c1 = dd1 / 25, r1 = dd1 % 25, i1 = r1 / 5, j1 = r1 % 5;
    const int off0 = c0 * (Hh * Ww) + i0 * Ww + j0;
    const int off1 = c1 * (Hh * Ww) + i1 * Ww + j1;

    const int* ln = lw_n + (size_t)o * cap;
    const float* ls = lw_s + (size_t)o * cap;

    float acc0 = 0.f, acc1 = 0.f, ssum = 0.f;
    int nA = 0, nB = 0; float sA = 0.f, sB = 0.f;
    if (e0 < e1)     { nA = ln[e0];     sA = ls[e0]; }
    if (e0 + 1 < e1) { nB = ln[e0 + 1]; sB = ls[e0 + 1]; }
    float xA0 = 0.f, xA1 = 0.f;
    if (e0 < e1) {
        int bb = nA / 3600, rem = nA - bb * 3600, hh = rem / 60, ww2 = rem - hh * 60;
        const float* xb = x + (size_t)bb * (C_ * Hh * Ww) + hh * Ww + ww2;
        xA0 = xb[off0]; if (has1) xA1 = xb[off1];
    }
    for (int e = e0; e < e1; ++e) {
        float xB0 = 0.f, xB1 = 0.f;
        if (e + 1 < e1) {
            int bb = nB / 3600, rem = nB - bb * 3600, hh = rem / 60, ww2 = rem - hh * 60;
            const float* xb = x + (size_t)bb * (C_ * Hh * Ww) + hh * Ww + ww2;
            xB0 = xb[off0]; if (has1) xB1 = xb[off1];
        }
        int nC = 0; float sC = 0.f;
        if (e + 2 < e1) { nC = ln[e + 2]; sC = ls[e + 2]; }
        ssum += sA; acc0 += sA * xA0; acc1 += sA * xA1;
        nA = nB; sA = sB; xA0 = xB0; xA1 = xB1;
        nB = nC; sB = sC;
    }
    if (e0 < e1) {
        const float invN = 1.0f / (float)Nn;
        atomicAdd(dout + NY + (size_t)o * Dd + d0, acc0 * invN - ssum * invN * w[o * Dd + d0]);
        if (has1)
            atomicAdd(dout + NY + (size_t)o * Dd + dd1, acc1 * invN - ssum * invN * w[o * Dd + dd1]);
    }
}

extern "C" void kernel_launch(void* const* d_in, const int* in_sizes, int n_in,
                              void* d_out, int out_size, void* d_ws, size_t ws_size,
                              hipStream_t stream) {
    (void)in_sizes; (void)n_in; (void)out_size;
    const float* x = (const float*)d_in[0];
    const float* w = (const float*)d_in[1];
    float* out = (float*)d_out;

    char* ws = (char*)d_ws;
    int*            count  = (int*)ws;                         // @0         (1,024 B)
    int*            acnt   = (int*)(ws + 1024);                // @1,024     (64 B)
    int*            ovcnt  = (int*)(ws + 1088);                // @1,088     (64 B)
    int*            ambig  = (int*)(ws + 1152);                // @1,152     (65,536 B)
    unsigned short* wpkH   = (unsigned short*)(ws + 66688);    // @66,688    (204,800 B)
    unsigned short* wpkL   = (unsigned short*)(ws + 271488);   // @271,488   (204,800 B)
    unsigned short* winner = (unsigned short*)(ws + 476288);   // @476,288   (230,400 B)
    float*          wsv    = (float*)(ws + 706688);            // @706,688   (460,800 B)
    int*            ovn    = (int*)(ws + 1167488);             // @1,167,488 (4,096 B)
    int*            ovo    = (int*)(ws + 1171584);             // @1,171,584 (4,096 B)
    float*          ovs    = (float*)(ws + 1175680);           // @1,175,680 (4,096 B)
    int*            hist   = (int*)(ws + 1179776);             // @1,179,776 (61,440 B)
    int*            gbase  = (int*)(ws + 1241216);             // @1,241,216 (61,440 B)
    const size_t base = 1302656;

    size_t avail = (ws_size > base) ? (ws_size - base) : 0;
    long long cap_ll = (long long)(avail / ((size_t)O_ * 8));
    int cap = (int)(cap_ll > 4096 ? 4096 : (cap_ll < 1 ? 1 : cap_ll));

    int*   lw_n = (int*)(ws + base);
    float* lw_s = (float*)(ws + base + (size_t)O_ * cap * 4);

    prep_kernel<<<dim3(25), dim3(256), 0, stream>>>(w, wpkH, wpkL, acnt, ovcnt, out);
    conv_mfma_kernel<<<dim3(B_ * Ho_), dim3(256), 0, stream>>>(x, wpkH, wpkL, out, winner, wsv,
                                                               acnt, ambig);
    fallback_kernel<<<dim3(256), dim3(256), 0, stream>>>(x, w, acnt, ambig, winner, wsv,
                                                         ovn, ovo, ovs, ovcnt);
    hist_kernel<<<dim3(NCHK), dim3(256), 0, stream>>>(winner, hist);
    scan_kernel<<<dim3(1), dim3(256), 0, stream>>>(hist, gbase, count, ovn, ovo, ovs, ovcnt,
                                                   lw_n, lw_s, cap);
    scatter_kernel<<<dim3(NCHK), dim3(256), 0, stream>>>(winner, wsv, gbase, lw_n, lw_s, cap);
    delta_part_kernel<<<dim3(O_ * NSL), dim3(256), 0, stream>>>(x, w, count, lw_n, lw_s, out, cap);
}